// Round 3
// baseline (148.817 us; speedup 1.0000x reference)
//
#include <hip/hip_runtime.h>
#include <math.h>

// X[8192,64], Y[8192,64] fp32.
// d2[i][j] = x2_i + y2_j - 2<x_i,y_j>;  out = mean_i sqrt(min_j d2) + mean_j sqrt(min_i d2)
//
// R3 structure: prep converts X,Y -> bf16 (ws) + x2/y2; mine is LDS-free and
// barrier-free — each wave holds its full 64x64 K=64 operands in registers
// (8+8 bf16x8 frags), loops 4 j-chunks with register double-buffered B, and
// writes PARTIAL mins to distinct slots (no atomics, no init needed: every
// slot written exactly once). finish tree-reduces partials + sqrt + mean.

#define NROWS 8192
#define DDIM  64
#define ITILES 64     // 8192 / 128
#define SLICES 16     // 8192 / 512
#define CHUNKS 4      // 4 x 128 j per block

typedef __bf16 bf16_t;
typedef bf16_t bf16x8 __attribute__((ext_vector_type(8)));
typedef float  f32x4  __attribute__((ext_vector_type(4)));

// ws layout (bytes):
// [0, 1M)        Xbf  (8192x64 bf16)
// [1M, 2M)       Ybf
// then floats:   x2[8192] | y2[8192] | rslab[8192*32] | cslab[128*8192]
// total ~7.1 MB

__global__ void prep_kernel(const float* __restrict__ X,
                            const float* __restrict__ Y,
                            bf16_t* __restrict__ Xbf, bf16_t* __restrict__ Ybf,
                            float* __restrict__ x2, float* __restrict__ y2,
                            float* __restrict__ out) {
  int t = blockIdx.x * blockDim.x + threadIdx.x;   // 0..65535
  int half = t >> 15;                              // 0: X, 1: Y
  int r = (t >> 2) & (NROWS - 1);
  int part = t & 3;                                // 16 elems per thread
  const float* src = half ? Y : X;
  bf16_t* dst = half ? Ybf : Xbf;
  float* sq = half ? y2 : x2;

  const float4* p = (const float4*)(src + r * DDIM + part * 16);
  float4 v0 = p[0], v1 = p[1], v2 = p[2], v3 = p[3];
  float s = 0.f;
  s = fmaf(v0.x, v0.x, s); s = fmaf(v0.y, v0.y, s);
  s = fmaf(v0.z, v0.z, s); s = fmaf(v0.w, v0.w, s);
  s = fmaf(v1.x, v1.x, s); s = fmaf(v1.y, v1.y, s);
  s = fmaf(v1.z, v1.z, s); s = fmaf(v1.w, v1.w, s);
  s = fmaf(v2.x, v2.x, s); s = fmaf(v2.y, v2.y, s);
  s = fmaf(v2.z, v2.z, s); s = fmaf(v2.w, v2.w, s);
  s = fmaf(v3.x, v3.x, s); s = fmaf(v3.y, v3.y, s);
  s = fmaf(v3.z, v3.z, s); s = fmaf(v3.w, v3.w, s);

  bf16x8 h0 = {(bf16_t)v0.x, (bf16_t)v0.y, (bf16_t)v0.z, (bf16_t)v0.w,
               (bf16_t)v1.x, (bf16_t)v1.y, (bf16_t)v1.z, (bf16_t)v1.w};
  bf16x8 h1 = {(bf16_t)v2.x, (bf16_t)v2.y, (bf16_t)v2.z, (bf16_t)v2.w,
               (bf16_t)v3.x, (bf16_t)v3.y, (bf16_t)v3.z, (bf16_t)v3.w};
  *(bf16x8*)&dst[r * DDIM + part * 16] = h0;
  *(bf16x8*)&dst[r * DDIM + part * 16 + 8] = h1;

  // reduce sum-of-squares across the 4 lanes of this row
  s += __shfl_xor(s, 1, 64);
  s += __shfl_xor(s, 2, 64);
  if (part == 0) sq[r] = s;
  if (t == 0) out[0] = 0.f;
}

__global__ __launch_bounds__(256, 2)
void mine_kernel(const bf16_t* __restrict__ Xbf, const bf16_t* __restrict__ Ybf,
                 const float* __restrict__ x2g, const float* __restrict__ y2g,
                 float* __restrict__ rslab, float* __restrict__ cslab) {
  const int tid = threadIdx.x;
  const int L = tid & 63;
  const int w = tid >> 6;
  const int lr = L & 15;
  const int q = L >> 4;
  const int itile = blockIdx.x & (ITILES - 1);
  const int slice = blockIdx.x >> 6;
  const int i0 = itile * 128;
  const int rgb = (w >> 1) * 64;   // wave row offset (half)
  const int cgb = (w & 1) * 64;    // wave col offset (half)
  const int jbase = slice * (CHUNKS * 128);

  // ---- A fragments: wave's 64 rows x K=64, fully register-resident ----
  bf16x8 Af[8];
#pragma unroll
  for (int a = 0; a < 4; ++a) {
    int row = i0 + rgb + a * 16 + lr;
#pragma unroll
    for (int h = 0; h < 2; ++h)
      Af[a * 2 + h] = *(const bf16x8*)&Xbf[row * DDIM + h * 32 + q * 8];
  }
  float x2r[16];
#pragma unroll
  for (int a = 0; a < 4; ++a)
#pragma unroll
    for (int p = 0; p < 4; ++p)
      x2r[a * 4 + p] = x2g[i0 + rgb + a * 16 + q * 4 + p];

  float rmin[16];
#pragma unroll
  for (int k = 0; k < 16; ++k) rmin[k] = INFINITY;

  bf16x8 Bc[8];
  float y2c[4];
  {
    int j0 = jbase;
#pragma unroll
    for (int b = 0; b < 4; ++b) {
      int row = j0 + cgb + b * 16 + lr;
#pragma unroll
      for (int h = 0; h < 2; ++h)
        Bc[b * 2 + h] = *(const bf16x8*)&Ybf[row * DDIM + h * 32 + q * 8];
      y2c[b] = y2g[row];
    }
  }

#pragma unroll
  for (int cc = 0; cc < CHUNKS; ++cc) {
    bf16x8 Bn[8];
    float y2n[4];
    if (cc < CHUNKS - 1) {
      int j0 = jbase + (cc + 1) * 128;
#pragma unroll
      for (int b = 0; b < 4; ++b) {
        int row = j0 + cgb + b * 16 + lr;
#pragma unroll
        for (int h = 0; h < 2; ++h)
          Bn[b * 2 + h] = *(const bf16x8*)&Ybf[row * DDIM + h * 32 + q * 8];
        y2n[b] = y2g[row];
      }
    }

    f32x4 acc[4][4];
#pragma unroll
    for (int a = 0; a < 4; ++a)
#pragma unroll
      for (int b = 0; b < 4; ++b) acc[a][b] = (f32x4){0.f, 0.f, 0.f, 0.f};

#pragma unroll
    for (int h = 0; h < 2; ++h)
#pragma unroll
      for (int a = 0; a < 4; ++a)
#pragma unroll
        for (int b = 0; b < 4; ++b)
          acc[a][b] = __builtin_amdgcn_mfma_f32_16x16x32_bf16(
              Af[a * 2 + h], Bc[b * 2 + h], acc[a][b], 0, 0, 0);

    // ---- epilogue (C/D: col = cgb+b*16+lr, row = a*16+q*4+p) ----
    float cmin[4] = {INFINITY, INFINITY, INFINITY, INFINITY};
#pragma unroll
    for (int a = 0; a < 4; ++a)
#pragma unroll
      for (int p = 0; p < 4; ++p) {
        float x2v = x2r[a * 4 + p];
        float rm = rmin[a * 4 + p];
#pragma unroll
        for (int b = 0; b < 4; ++b) {
          float s = acc[a][b][p];
          rm = fminf(rm, fmaf(-2.f, s, y2c[b]));
          cmin[b] = fminf(cmin[b], fmaf(-2.f, s, x2v));
        }
        rmin[a * 4 + p] = rm;
      }
    // col-min across the wave's 64 rows (reduce over q), then lane q*16+lr
    // takes col group b=q  ->  wave stores 64 contiguous floats
#pragma unroll
    for (int b = 0; b < 4; ++b) {
      cmin[b] = fminf(cmin[b], __shfl_xor(cmin[b], 16, 64));
      cmin[b] = fminf(cmin[b], __shfl_xor(cmin[b], 32, 64));
    }
    float v = cmin[0];
    if (q == 1) v = cmin[1];
    else if (q == 2) v = cmin[2];
    else if (q == 3) v = cmin[3];
    int j0 = jbase + cc * 128;
    cslab[(itile * 2 + (w >> 1)) * NROWS + j0 + cgb + L] = v;

    if (cc < CHUNKS - 1) {
#pragma unroll
      for (int k = 0; k < 8; ++k) Bc[k] = Bn[k];
#pragma unroll
      for (int b = 0; b < 4; ++b) y2c[b] = y2n[b];
    }
  }

  // ---- row mins: reduce across the 16 col-lanes, store partial ----
#pragma unroll
  for (int a = 0; a < 4; ++a)
#pragma unroll
    for (int p = 0; p < 4; ++p) {
      float v = rmin[a * 4 + p];
      v = fminf(v, __shfl_xor(v, 1, 64));
      v = fminf(v, __shfl_xor(v, 2, 64));
      v = fminf(v, __shfl_xor(v, 4, 64));
      v = fminf(v, __shfl_xor(v, 8, 64));
      if (lr == 0)
        rslab[(i0 + rgb + a * 16 + q * 4 + p) * (SLICES * 2) + slice * 2 + (w & 1)] = v;
    }
}

__global__ void finish_kernel(const float* __restrict__ x2,
                              const float* __restrict__ y2,
                              const float* __restrict__ rslab,
                              const float* __restrict__ cslab,
                              float* __restrict__ out) {
  int t = blockIdx.x * blockDim.x + threadIdx.x;  // 0..16383
  float d;
  if (t < NROWS) {
    const float* rp = rslab + t * (SLICES * 2);
    float m = INFINITY;
#pragma unroll
    for (int k = 0; k < SLICES * 2; ++k) m = fminf(m, rp[k]);
    d = sqrtf(fmaxf(x2[t] + m, 0.f));
  } else {
    int j = t - NROWS;
    float m = INFINITY;
#pragma unroll 8
    for (int p = 0; p < 128; ++p) m = fminf(m, cslab[p * NROWS + j]);
    d = sqrtf(fmaxf(y2[j] + m, 0.f));
  }
  float v = d * (1.0f / 8192.0f);
#pragma unroll
  for (int off = 32; off > 0; off >>= 1) v += __shfl_down(v, off, 64);
  __shared__ float partial[4];
  if ((threadIdx.x & 63) == 0) partial[threadIdx.x >> 6] = v;
  __syncthreads();
  if (threadIdx.x == 0)
    atomicAdd(out, partial[0] + partial[1] + partial[2] + partial[3]);
}

extern "C" void kernel_launch(void* const* d_in, const int* in_sizes, int n_in,
                              void* d_out, int out_size, void* d_ws, size_t ws_size,
                              hipStream_t stream) {
  const float* X = (const float*)d_in[0];
  const float* Y = (const float*)d_in[1];
  float* out = (float*)d_out;

  char* wsb = (char*)d_ws;
  bf16_t* Xbf = (bf16_t*)wsb;
  bf16_t* Ybf = (bf16_t*)(wsb + (size_t)NROWS * DDIM * 2);
  float* x2 = (float*)(wsb + 2 * (size_t)NROWS * DDIM * 2);
  float* y2 = x2 + NROWS;
  float* rslab = y2 + NROWS;                 // [8192][32]
  float* cslab = rslab + NROWS * (SLICES * 2);  // [128][8192]

  prep_kernel<<<(2 * NROWS * 4) / 256, 256, 0, stream>>>(X, Y, Xbf, Ybf, x2, y2, out);
  mine_kernel<<<ITILES * SLICES, 256, 0, stream>>>(Xbf, Ybf, x2, y2, rslab, cslab);
  finish_kernel<<<(2 * NROWS) / 256, 256, 0, stream>>>(x2, y2, rslab, cslab, out);
}

// Round 4
// 91.590 us; speedup vs baseline: 1.6248x; 1.6248x over previous
//
#include <hip/hip_runtime.h>
#include <math.h>

// X[8192,64], Y[8192,64] fp32.
// d2[i][j] = x2_i + y2_j - 2<x_i,y_j>;  out = mean_i sqrt(min_j d2) + mean_j sqrt(min_i d2)
//
// R4: prep converts X,Y->bf16 + squares. mine: A register-persistent (64 rows x
// K64 = 32 VGPR/wave), B LDS-staged per 128-j chunk (shared by all 4 waves, no
// redundant L2 fetch), 16x16x32 bf16 MFMA, epilogue tracks min(y2-2s) rows /
// min(x2-2s) cols. No atomics: partial-min slabs, each slot written exactly
// once (no init needed). reduceC collapses cslab 128->16 coalesced; finish does
// 16-deep mins + sqrt + mean. Spill fix vs R3: arch VGPR ~110 < 128 cap.

#define NROWS 8192
#define DDIM  64
#define ITILES 64     // 8192 / 128 i-rows per block
#define SLICES 16     // j: 16 slices x 512
#define CHUNKS 4      // 4 x 128 j per block
#define LSTR 72       // LDS row stride in bf16: 144 B (16B-aligned, bank-stagger)

typedef __bf16 bf16_t;
typedef bf16_t bf16x8 __attribute__((ext_vector_type(8)));
typedef float  f32x4  __attribute__((ext_vector_type(4)));

// ws layout: [0,1M) Xbf | [1M,2M) Ybf | floats: x2[8192] y2[8192]
//            rslab[16][8192][2] | cslab[128][8192] | cmin16[16][8192]

__global__ void prep_kernel(const float* __restrict__ X,
                            const float* __restrict__ Y,
                            bf16_t* __restrict__ Xbf, bf16_t* __restrict__ Ybf,
                            float* __restrict__ x2, float* __restrict__ y2,
                            float* __restrict__ out) {
  int t = blockIdx.x * blockDim.x + threadIdx.x;   // 0..65535
  int half = t >> 15;                              // 0: X, 1: Y
  int r = (t >> 2) & (NROWS - 1);
  int part = t & 3;                                // 16 elems per thread
  const float* src = half ? Y : X;
  bf16_t* dst = half ? Ybf : Xbf;
  float* sq = half ? y2 : x2;

  const float4* p = (const float4*)(src + r * DDIM + part * 16);
  float4 v0 = p[0], v1 = p[1], v2 = p[2], v3 = p[3];
  float s = 0.f;
  s = fmaf(v0.x, v0.x, s); s = fmaf(v0.y, v0.y, s);
  s = fmaf(v0.z, v0.z, s); s = fmaf(v0.w, v0.w, s);
  s = fmaf(v1.x, v1.x, s); s = fmaf(v1.y, v1.y, s);
  s = fmaf(v1.z, v1.z, s); s = fmaf(v1.w, v1.w, s);
  s = fmaf(v2.x, v2.x, s); s = fmaf(v2.y, v2.y, s);
  s = fmaf(v2.z, v2.z, s); s = fmaf(v2.w, v2.w, s);
  s = fmaf(v3.x, v3.x, s); s = fmaf(v3.y, v3.y, s);
  s = fmaf(v3.z, v3.z, s); s = fmaf(v3.w, v3.w, s);

  bf16x8 h0 = {(bf16_t)v0.x, (bf16_t)v0.y, (bf16_t)v0.z, (bf16_t)v0.w,
               (bf16_t)v1.x, (bf16_t)v1.y, (bf16_t)v1.z, (bf16_t)v1.w};
  bf16x8 h1 = {(bf16_t)v2.x, (bf16_t)v2.y, (bf16_t)v2.z, (bf16_t)v2.w,
               (bf16_t)v3.x, (bf16_t)v3.y, (bf16_t)v3.z, (bf16_t)v3.w};
  *(bf16x8*)&dst[r * DDIM + part * 16] = h0;
  *(bf16x8*)&dst[r * DDIM + part * 16 + 8] = h1;

  s += __shfl_xor(s, 1, 64);
  s += __shfl_xor(s, 2, 64);
  if (part == 0) sq[r] = s;
  if (t == 0) out[0] = 0.f;
}

__global__ __launch_bounds__(256, 2)
void mine_kernel(const bf16_t* __restrict__ Xbf, const bf16_t* __restrict__ Ybf,
                 const float* __restrict__ x2g, const float* __restrict__ y2g,
                 float* __restrict__ rslab, float* __restrict__ cslab) {
  __shared__ bf16_t Ys[128 * LSTR];   // 18 KB

  const int tid = threadIdx.x;
  const int L = tid & 63;
  const int w = tid >> 6;
  const int lr = L & 15;
  const int q = L >> 4;
  const int rh = w >> 1;              // wave row-half (0/1)
  const int ch = w & 1;               // wave col-half (0/1)
  const int itile = blockIdx.x & (ITILES - 1);
  const int slice = blockIdx.x >> 6;
  const int i0 = itile * 128;
  const int rgb = rh * 64;
  const int cgb = ch * 64;
  const int jbase = slice * (CHUNKS * 128);

  // ---- A fragments: wave's 64 rows x K=64, register-persistent ----
  bf16x8 Af[8];
#pragma unroll
  for (int a = 0; a < 4; ++a) {
    int row = i0 + rgb + a * 16 + lr;
#pragma unroll
    for (int h = 0; h < 2; ++h)
      Af[a * 2 + h] = *(const bf16x8*)&Xbf[row * DDIM + h * 32 + q * 8];
  }
  float x2r[16];
#pragma unroll
  for (int a = 0; a < 4; ++a) {
    float4 v = *(const float4*)&x2g[i0 + rgb + a * 16 + q * 4];
    x2r[a * 4 + 0] = v.x; x2r[a * 4 + 1] = v.y;
    x2r[a * 4 + 2] = v.z; x2r[a * 4 + 3] = v.w;
  }
  float rmin[16];
#pragma unroll
  for (int k = 0; k < 16; ++k) rmin[k] = INFINITY;

  for (int cc = 0; cc < CHUNKS; ++cc) {
    const int j0 = jbase + cc * 128;
    __syncthreads();               // previous chunk's LDS consumption done
    // ---- stage B chunk: 128 rows x 64 bf16, 16B per thread per pass ----
#pragma unroll
    for (int p = 0; p < 4; ++p) {
      int f = p * 256 + tid;
      int r = f >> 3, c = f & 7;
      *(bf16x8*)&Ys[r * LSTR + c * 8] = *(const bf16x8*)&Ybf[(j0 + r) * DDIM + c * 8];
    }
    __syncthreads();

    float y2c[4];
#pragma unroll
    for (int b = 0; b < 4; ++b) y2c[b] = y2g[j0 + cgb + b * 16 + lr];

    f32x4 acc[4][4];
#pragma unroll
    for (int a = 0; a < 4; ++a)
#pragma unroll
      for (int b = 0; b < 4; ++b) acc[a][b] = (f32x4){0.f, 0.f, 0.f, 0.f};

#pragma unroll
    for (int b = 0; b < 4; ++b) {
      bf16x8 B0 = *(const bf16x8*)&Ys[(cgb + b * 16 + lr) * LSTR + q * 8];
      bf16x8 B1 = *(const bf16x8*)&Ys[(cgb + b * 16 + lr) * LSTR + 32 + q * 8];
#pragma unroll
      for (int a = 0; a < 4; ++a) {
        acc[a][b] = __builtin_amdgcn_mfma_f32_16x16x32_bf16(Af[a * 2 + 0], B0, acc[a][b], 0, 0, 0);
        acc[a][b] = __builtin_amdgcn_mfma_f32_16x16x32_bf16(Af[a * 2 + 1], B1, acc[a][b], 0, 0, 0);
      }
    }

    // ---- epilogue (C/D: col = lr, row = q*4+p within 16x16) ----
    float cmin[4] = {INFINITY, INFINITY, INFINITY, INFINITY};
#pragma unroll
    for (int a = 0; a < 4; ++a)
#pragma unroll
      for (int p = 0; p < 4; ++p) {
        float x2v = x2r[a * 4 + p];
        float rm = rmin[a * 4 + p];
#pragma unroll
        for (int b = 0; b < 4; ++b) {
          float s = acc[a][b][p];
          rm = fminf(rm, fmaf(-2.f, s, y2c[b]));
          cmin[b] = fminf(cmin[b], fmaf(-2.f, s, x2v));
        }
        rmin[a * 4 + p] = rm;
      }
    // col-min across wave's 64 rows: reduce over q, lane q*16+lr takes b=q
#pragma unroll
    for (int b = 0; b < 4; ++b) {
      cmin[b] = fminf(cmin[b], __shfl_xor(cmin[b], 16, 64));
      cmin[b] = fminf(cmin[b], __shfl_xor(cmin[b], 32, 64));
    }
    float v = cmin[0];
    if (q == 1) v = cmin[1];
    else if (q == 2) v = cmin[2];
    else if (q == 3) v = cmin[3];
    cslab[(itile * 2 + rh) * NROWS + j0 + cgb + L] = v;
  }

  // ---- row mins: reduce across 16 col-lanes, store [slice][row][ch] ----
#pragma unroll
  for (int a = 0; a < 4; ++a)
#pragma unroll
    for (int p = 0; p < 4; ++p) {
      float v = rmin[a * 4 + p];
      v = fminf(v, __shfl_xor(v, 1, 64));
      v = fminf(v, __shfl_xor(v, 2, 64));
      v = fminf(v, __shfl_xor(v, 4, 64));
      v = fminf(v, __shfl_xor(v, 8, 64));
      if (lr == 0)
        rslab[slice * (NROWS * 2) + (i0 + rgb + a * 16 + q * 4 + p) * 2 + ch] = v;
    }
}

// cslab[128][8192] -> cmin16[16][8192], coalesced
__global__ void reducec_kernel(const float* __restrict__ cslab,
                               float* __restrict__ cmin16) {
  int t = blockIdx.x * blockDim.x + threadIdx.x;  // 0..131071
  int g = t >> 13, j = t & (NROWS - 1);
  float m = INFINITY;
#pragma unroll
  for (int k = 0; k < 8; ++k) m = fminf(m, cslab[(g * 8 + k) * NROWS + j]);
  cmin16[g * NROWS + j] = m;
}

__global__ void finish_kernel(const float* __restrict__ x2,
                              const float* __restrict__ y2,
                              const float* __restrict__ rslab,
                              const float* __restrict__ cmin16,
                              float* __restrict__ out) {
  int t = blockIdx.x * blockDim.x + threadIdx.x;  // 0..16383 (128x128)
  float d;
  if (t < NROWS) {
    float m = INFINITY;
#pragma unroll
    for (int g = 0; g < SLICES; ++g) {
      float2 v = *(const float2*)&rslab[g * (NROWS * 2) + t * 2];
      m = fminf(m, fminf(v.x, v.y));
    }
    d = sqrtf(fmaxf(x2[t] + m, 0.f));
  } else {
    int j = t - NROWS;
    float m = INFINITY;
#pragma unroll
    for (int g = 0; g < 16; ++g) m = fminf(m, cmin16[g * NROWS + j]);
    d = sqrtf(fmaxf(y2[j] + m, 0.f));
  }
  float v = d * (1.0f / 8192.0f);
#pragma unroll
  for (int off = 32; off > 0; off >>= 1) v += __shfl_down(v, off, 64);
  __shared__ float partial[2];
  if ((threadIdx.x & 63) == 0) partial[threadIdx.x >> 6] = v;
  __syncthreads();
  if (threadIdx.x == 0) atomicAdd(out, partial[0] + partial[1]);
}

extern "C" void kernel_launch(void* const* d_in, const int* in_sizes, int n_in,
                              void* d_out, int out_size, void* d_ws, size_t ws_size,
                              hipStream_t stream) {
  const float* X = (const float*)d_in[0];
  const float* Y = (const float*)d_in[1];
  float* out = (float*)d_out;

  char* wsb = (char*)d_ws;
  bf16_t* Xbf = (bf16_t*)wsb;
  bf16_t* Ybf = (bf16_t*)(wsb + (size_t)NROWS * DDIM * 2);
  float* x2 = (float*)(wsb + 2 * (size_t)NROWS * DDIM * 2);
  float* y2 = x2 + NROWS;
  float* rslab = y2 + NROWS;                    // [16][8192][2]  1 MB
  float* cslab = rslab + SLICES * NROWS * 2;    // [128][8192]    4 MB
  float* cmin16 = cslab + 128 * NROWS;          // [16][8192]     512 KB

  prep_kernel<<<(2 * NROWS * 4) / 256, 256, 0, stream>>>(X, Y, Xbf, Ybf, x2, y2, out);
  mine_kernel<<<ITILES * SLICES, 256, 0, stream>>>(Xbf, Ybf, x2, y2, rslab, cslab);
  reducec_kernel<<<(16 * NROWS) / 256, 256, 0, stream>>>(cslab, cmin16);
  finish_kernel<<<128, 128, 0, stream>>>(x2, y2, rslab, cmin16, out);
}

// Round 5
// 85.034 us; speedup vs baseline: 1.7501x; 1.0771x over previous
//
#include <hip/hip_runtime.h>
#include <math.h>

// X[8192,64], Y[8192,64] fp32.
// d2[i][j] = x2_i + y2_j - 2<x_i,y_j>;  out = mean_i sqrt(min_j d2) + mean_j sqrt(min_i d2)
//
// R5: 3 kernels. prep: fp32->bf16 + row squares. mine: A register-persistent
// (64 rows x K64), B LDS double-buffered (one barrier/chunk, prefetch to regs
// during compute), 16x16x32 bf16 MFMA, epilogue tracks min(y2-2s)/min(x2-2s).
// No atomics in mine: partial slabs, each slot written once. finish: rows via
// [slice][row][2] coalesced float2; cols reduce cslab[128][8192] coalesced
// with LDS 4-segment combine. Harness d_ws 0xAA fill (~41us, 268MB) is inside
// the timed window and is a fixed floor we cannot affect.

#define NROWS 8192
#define DDIM  64
#define ITILES 64     // 8192 / 128 i-rows per block
#define SLICES 16     // j: 16 slices x 512
#define CHUNKS 4      // 4 x 128 j per block
#define LSTR 72       // LDS row stride (bf16): 144 B -> 16B-aligned, 2-way-max banks

typedef __bf16 bf16_t;
typedef bf16_t bf16x8 __attribute__((ext_vector_type(8)));
typedef float  f32x4  __attribute__((ext_vector_type(4)));

__global__ void prep_kernel(const float* __restrict__ X,
                            const float* __restrict__ Y,
                            bf16_t* __restrict__ Xbf, bf16_t* __restrict__ Ybf,
                            float* __restrict__ x2, float* __restrict__ y2,
                            float* __restrict__ out) {
  int t = blockIdx.x * blockDim.x + threadIdx.x;   // 0..65535
  int half = t >> 15;                              // 0: X, 1: Y
  int r = (t >> 2) & (NROWS - 1);
  int part = t & 3;                                // 16 elems per thread
  const float* src = half ? Y : X;
  bf16_t* dst = half ? Ybf : Xbf;
  float* sq = half ? y2 : x2;

  const float4* p = (const float4*)(src + r * DDIM + part * 16);
  float4 v0 = p[0], v1 = p[1], v2 = p[2], v3 = p[3];
  float s = 0.f;
  s = fmaf(v0.x, v0.x, s); s = fmaf(v0.y, v0.y, s);
  s = fmaf(v0.z, v0.z, s); s = fmaf(v0.w, v0.w, s);
  s = fmaf(v1.x, v1.x, s); s = fmaf(v1.y, v1.y, s);
  s = fmaf(v1.z, v1.z, s); s = fmaf(v1.w, v1.w, s);
  s = fmaf(v2.x, v2.x, s); s = fmaf(v2.y, v2.y, s);
  s = fmaf(v2.z, v2.z, s); s = fmaf(v2.w, v2.w, s);
  s = fmaf(v3.x, v3.x, s); s = fmaf(v3.y, v3.y, s);
  s = fmaf(v3.z, v3.z, s); s = fmaf(v3.w, v3.w, s);

  bf16x8 h0 = {(bf16_t)v0.x, (bf16_t)v0.y, (bf16_t)v0.z, (bf16_t)v0.w,
               (bf16_t)v1.x, (bf16_t)v1.y, (bf16_t)v1.z, (bf16_t)v1.w};
  bf16x8 h1 = {(bf16_t)v2.x, (bf16_t)v2.y, (bf16_t)v2.z, (bf16_t)v2.w,
               (bf16_t)v3.x, (bf16_t)v3.y, (bf16_t)v3.z, (bf16_t)v3.w};
  *(bf16x8*)&dst[r * DDIM + part * 16] = h0;
  *(bf16x8*)&dst[r * DDIM + part * 16 + 8] = h1;

  s += __shfl_xor(s, 1, 64);
  s += __shfl_xor(s, 2, 64);
  if (part == 0) sq[r] = s;
  if (t == 0) out[0] = 0.f;
}

__global__ __launch_bounds__(256, 2)
void mine_kernel(const bf16_t* __restrict__ Xbf, const bf16_t* __restrict__ Ybf,
                 const float* __restrict__ x2g, const float* __restrict__ y2g,
                 float* __restrict__ rslab, float* __restrict__ cslab) {
  __shared__ bf16_t Ys[2][128 * LSTR];   // 2 x 18 KB

  const int tid = threadIdx.x;
  const int L = tid & 63;
  const int w = tid >> 6;
  const int lr = L & 15;
  const int q = L >> 4;
  const int rh = w >> 1;              // wave row-half
  const int ch = w & 1;               // wave col-half
  const int itile = blockIdx.x & (ITILES - 1);
  const int slice = blockIdx.x >> 6;
  const int i0 = itile * 128;
  const int rgb = rh * 64;
  const int cgb = ch * 64;
  const int jbase = slice * (CHUNKS * 128);

  // ---- A fragments: register-persistent ----
  bf16x8 Af[8];
#pragma unroll
  for (int a = 0; a < 4; ++a) {
    int row = i0 + rgb + a * 16 + lr;
#pragma unroll
    for (int h = 0; h < 2; ++h)
      Af[a * 2 + h] = *(const bf16x8*)&Xbf[row * DDIM + h * 32 + q * 8];
  }
  float x2r[16];
#pragma unroll
  for (int a = 0; a < 4; ++a) {
    float4 v = *(const float4*)&x2g[i0 + rgb + a * 16 + q * 4];
    x2r[a * 4 + 0] = v.x; x2r[a * 4 + 1] = v.y;
    x2r[a * 4 + 2] = v.z; x2r[a * 4 + 3] = v.w;
  }
  // prefetch y2 for all chunks
  float y2all[CHUNKS][4];
#pragma unroll
  for (int cc = 0; cc < CHUNKS; ++cc)
#pragma unroll
    for (int b = 0; b < 4; ++b)
      y2all[cc][b] = y2g[jbase + cc * 128 + cgb + b * 16 + lr];

  float rmin[16];
#pragma unroll
  for (int k = 0; k < 16; ++k) rmin[k] = INFINITY;

  // ---- prologue: stage chunk 0 ----
  bf16x8 Bst[4];
#pragma unroll
  for (int p = 0; p < 4; ++p) {
    int f = p * 256 + tid;
    Bst[p] = *(const bf16x8*)&Ybf[(jbase + (f >> 3)) * DDIM + (f & 7) * 8];
  }
#pragma unroll
  for (int p = 0; p < 4; ++p) {
    int f = p * 256 + tid;
    *(bf16x8*)&Ys[0][(f >> 3) * LSTR + (f & 7) * 8] = Bst[p];
  }
  __syncthreads();

  for (int cc = 0; cc < CHUNKS; ++cc) {
    const bf16_t* Yb = Ys[cc & 1];
    // issue next chunk's global loads now; latency hidden by compute
    if (cc + 1 < CHUNKS) {
      int j0n = jbase + (cc + 1) * 128;
#pragma unroll
      for (int p = 0; p < 4; ++p) {
        int f = p * 256 + tid;
        Bst[p] = *(const bf16x8*)&Ybf[(j0n + (f >> 3)) * DDIM + (f & 7) * 8];
      }
    }

    f32x4 acc[4][4];
#pragma unroll
    for (int a = 0; a < 4; ++a)
#pragma unroll
      for (int b = 0; b < 4; ++b) acc[a][b] = (f32x4){0.f, 0.f, 0.f, 0.f};

#pragma unroll
    for (int b = 0; b < 4; ++b) {
      bf16x8 B0 = *(const bf16x8*)&Yb[(cgb + b * 16 + lr) * LSTR + q * 8];
      bf16x8 B1 = *(const bf16x8*)&Yb[(cgb + b * 16 + lr) * LSTR + 32 + q * 8];
#pragma unroll
      for (int a = 0; a < 4; ++a) {
        acc[a][b] = __builtin_amdgcn_mfma_f32_16x16x32_bf16(Af[a * 2 + 0], B0, acc[a][b], 0, 0, 0);
        acc[a][b] = __builtin_amdgcn_mfma_f32_16x16x32_bf16(Af[a * 2 + 1], B1, acc[a][b], 0, 0, 0);
      }
    }

    // ---- epilogue (C/D: col = lr within 16, row = q*4+p) ----
    float cmin[4] = {INFINITY, INFINITY, INFINITY, INFINITY};
#pragma unroll
    for (int a = 0; a < 4; ++a)
#pragma unroll
      for (int p = 0; p < 4; ++p) {
        float x2v = x2r[a * 4 + p];
        float rm = rmin[a * 4 + p];
#pragma unroll
        for (int b = 0; b < 4; ++b) {
          float s = acc[a][b][p];
          rm = fminf(rm, fmaf(-2.f, s, y2all[cc][b]));
          cmin[b] = fminf(cmin[b], fmaf(-2.f, s, x2v));
        }
        rmin[a * 4 + p] = rm;
      }
#pragma unroll
    for (int b = 0; b < 4; ++b) {
      cmin[b] = fminf(cmin[b], __shfl_xor(cmin[b], 16, 64));
      cmin[b] = fminf(cmin[b], __shfl_xor(cmin[b], 32, 64));
    }
    float v = cmin[0];
    if (q == 1) v = cmin[1];
    else if (q == 2) v = cmin[2];
    else if (q == 3) v = cmin[3];
    cslab[(itile * 2 + rh) * NROWS + jbase + cc * 128 + cgb + L] = v;

    // ---- write prefetched chunk into the other buffer, single barrier ----
    if (cc + 1 < CHUNKS) {
      bf16_t* Yn = Ys[(cc + 1) & 1];
#pragma unroll
      for (int p = 0; p < 4; ++p) {
        int f = p * 256 + tid;
        *(bf16x8*)&Yn[(f >> 3) * LSTR + (f & 7) * 8] = Bst[p];
      }
      __syncthreads();
    }
  }

  // ---- row mins: reduce across 16 col-lanes, store [slice][row][ch] ----
#pragma unroll
  for (int a = 0; a < 4; ++a)
#pragma unroll
    for (int p = 0; p < 4; ++p) {
      float v = rmin[a * 4 + p];
      v = fminf(v, __shfl_xor(v, 1, 64));
      v = fminf(v, __shfl_xor(v, 2, 64));
      v = fminf(v, __shfl_xor(v, 4, 64));
      v = fminf(v, __shfl_xor(v, 8, 64));
      if (lr == 0)
        rslab[slice * (NROWS * 2) + (i0 + rgb + a * 16 + q * 4 + p) * 2 + ch] = v;
    }
}

// blocks [0,32): rows (256 rows each). blocks [32,160): cols (64 cols each,
// 4 thread-segments x 32 partials, LDS combine).
__global__ void finish_kernel(const float* __restrict__ x2,
                              const float* __restrict__ y2,
                              const float* __restrict__ rslab,
                              const float* __restrict__ cslab,
                              float* __restrict__ out) {
  const int b = blockIdx.x;
  const int tid = threadIdx.x;
  if (b < 32) {
    int row = b * 256 + tid;
    float m = INFINITY;
#pragma unroll
    for (int g = 0; g < SLICES; ++g) {
      float2 v = *(const float2*)&rslab[g * (NROWS * 2) + row * 2];
      m = fminf(m, fminf(v.x, v.y));
    }
    float v = sqrtf(fmaxf(x2[row] + m, 0.f)) * (1.0f / 8192.0f);
#pragma unroll
    for (int off = 32; off > 0; off >>= 1) v += __shfl_down(v, off, 64);
    __shared__ float partial[4];
    if ((tid & 63) == 0) partial[tid >> 6] = v;
    __syncthreads();
    if (tid == 0)
      atomicAdd(out, partial[0] + partial[1] + partial[2] + partial[3]);
  } else {
    int j = (b - 32) * 64 + (tid & 63);
    int seg = tid >> 6;
    float m = INFINITY;
#pragma unroll
    for (int k = 0; k < 32; ++k)
      m = fminf(m, cslab[(seg * 32 + k) * NROWS + j]);
    __shared__ float red[4][64];
    red[seg][tid & 63] = m;
    __syncthreads();
    if (tid < 64) {
      float mc = fminf(fminf(red[0][tid], red[1][tid]),
                       fminf(red[2][tid], red[3][tid]));
      float v = sqrtf(fmaxf(y2[j] + mc, 0.f)) * (1.0f / 8192.0f);
#pragma unroll
      for (int off = 32; off > 0; off >>= 1) v += __shfl_down(v, off, 64);
      if (tid == 0) atomicAdd(out, v);
    }
  }
}

extern "C" void kernel_launch(void* const* d_in, const int* in_sizes, int n_in,
                              void* d_out, int out_size, void* d_ws, size_t ws_size,
                              hipStream_t stream) {
  const float* X = (const float*)d_in[0];
  const float* Y = (const float*)d_in[1];
  float* out = (float*)d_out;

  char* wsb = (char*)d_ws;
  bf16_t* Xbf = (bf16_t*)wsb;
  bf16_t* Ybf = (bf16_t*)(wsb + (size_t)NROWS * DDIM * 2);
  float* x2 = (float*)(wsb + 2 * (size_t)NROWS * DDIM * 2);
  float* y2 = x2 + NROWS;
  float* rslab = y2 + NROWS;                    // [16][8192][2]  1 MB
  float* cslab = rslab + SLICES * NROWS * 2;    // [128][8192]    4 MB

  prep_kernel<<<(2 * NROWS * 4) / 256, 256, 0, stream>>>(X, Y, Xbf, Ybf, x2, y2, out);
  mine_kernel<<<ITILES * SLICES, 256, 0, stream>>>(Xbf, Ybf, x2, y2, rslab, cslab);
  finish_kernel<<<160, 256, 0, stream>>>(x2, y2, rslab, cslab, out);
}